// Round 1
// baseline (2879.688 us; speedup 1.0000x reference)
//
#include <hip/hip_runtime.h>
#include <hip/hip_bf16.h>

#define B_ 128
#define N_ 1024
#define E_ 300
#define U_ 128
#define M_ (B_ * N_)   // 131072

typedef __attribute__((ext_vector_type(8))) short bf16x8;
typedef __attribute__((ext_vector_type(4))) float f32x4;
typedef _Float16 h2_t __attribute__((ext_vector_type(2)));

#if defined(__has_builtin)
#if __has_builtin(__builtin_amdgcn_fdot2)
#define HAVE_FDOT2 1
#endif
#endif
#ifndef HAVE_FDOT2
#define HAVE_FDOT2 0
#endif

__device__ __forceinline__ short f2bf(float f) {
  unsigned u = __builtin_bit_cast(unsigned, f);
  u = (u + 0x7fffu + ((u >> 16) & 1u)) >> 16;
  return (short)u;
}

__device__ __forceinline__ float hsig(float z) {
  float v = __builtin_fmaf(z, 0.2f, 0.5f);
  v = v < 0.f ? 0.f : v;
  v = v > 1.f ? 1.f : v;
  return v;
}

__device__ __forceinline__ float tanh_fast(float x) {
  // tanh(x) = 1 - 2/(exp(2x)+1); exp->v_exp_f32, rcp->v_rcp_f32
  float p = __expf(2.f * x);
  return 1.f - 2.f * __builtin_amdgcn_rcpf(p + 1.f);
}

// ---------------- Kernel 1: x = relu(state @ Tk) -> H (d_out) and C (ws) ---
// A: (M_, 300) fp32, W: (300, 128) fp32.  BM=64, BN=128, BK=32 (K padded).
__global__ __launch_bounds__(256) void x_gemm(
    const float* __restrict__ A, const float* __restrict__ W,
    float* __restrict__ H, float* __restrict__ C) {
  __shared__ __align__(16) short As[64][40];    // [m][k] bf16, pad 40
  __shared__ __align__(16) short Ws[128][40];   // transposed: [n][k] bf16
  const int tid = threadIdx.x;
  const int m0 = blockIdx.x * 64;
  f32x4 acc[8] = {};
  const int lane = tid & 63, wv = tid >> 6;
  const int lr = lane & 15, lg = lane >> 4;

  for (int kc = 0; kc < 10; ++kc) {
    const int k0 = kc * 32;
    // stage A tile 64x32 (8 elems/thread)
    {
      const int row = tid >> 2, kk = (tid & 3) * 8;
      const float* src = A + (size_t)(m0 + row) * E_ + k0 + kk;
      bf16x8 v;
      if (k0 + 32 <= E_) {
#pragma unroll
        for (int i = 0; i < 8; ++i) v[i] = f2bf(src[i]);
      } else {
#pragma unroll
        for (int i = 0; i < 8; ++i)
          v[i] = (k0 + kk + i < E_) ? f2bf(src[i]) : (short)0;
      }
      *(bf16x8*)&As[row][kk] = v;
    }
    // stage W tile 32x128 transposed (2 slots of 8 elems/thread)
#pragma unroll
    for (int s = 0; s < 2; ++s) {
      const int slot = tid + s * 256;
      const int n = slot & 127, kg = slot >> 7;   // kg 0..3
      bf16x8 v;
      if (k0 + 32 <= E_) {
#pragma unroll
        for (int i = 0; i < 8; ++i) v[i] = f2bf(W[(k0 + kg * 8 + i) * U_ + n]);
      } else {
#pragma unroll
        for (int i = 0; i < 8; ++i) {
          const int k = k0 + kg * 8 + i;
          v[i] = (k < E_) ? f2bf(W[k * U_ + n]) : (short)0;
        }
      }
      *(bf16x8*)&Ws[n][kg * 8] = v;
    }
    __syncthreads();
    // MFMA: wave wv handles rows [wv*16, wv*16+16), all 128 cols
    bf16x8 a = *(const bf16x8*)&As[wv * 16 + lr][lg * 8];
#pragma unroll
    for (int nt = 0; nt < 8; ++nt) {
      bf16x8 b = *(const bf16x8*)&Ws[nt * 16 + lr][lg * 8];
      acc[nt] = __builtin_amdgcn_mfma_f32_16x16x32_bf16(a, b, acc[nt], 0, 0, 0);
    }
    __syncthreads();
  }
  // epilogue: C/D layout col = lane&15, row = (lane>>4)*4 + reg
#pragma unroll
  for (int nt = 0; nt < 8; ++nt) {
#pragma unroll
    for (int r = 0; r < 4; ++r) {
      const int m = m0 + wv * 16 + lg * 4 + r;
      const int n = nt * 16 + lr;
      float v = acc[nt][r];
      v = v > 0.f ? v : 0.f;
      H[(size_t)m * U_ + n] = v;
      C[(size_t)m * U_ + n] = v;
    }
  }
}

// ---------------- Kernel 2: per-batch sequential tree-LSTM scan ------------
// One workgroup per batch. 640 threads; thread j owns z-row j with its
// 384 weights (K[j,0:128] ++ R[j,0:256]) resident in registers as f16 pairs.
__global__ __launch_bounds__(640, 1) void tree_scan(
    const float* __restrict__ Wk,    // (640,128)
    const float* __restrict__ Wr,    // (640,256)
    const float* __restrict__ bias,  // (640,1)
    const int*   __restrict__ child, // (B,N,2)
    const int*   __restrict__ nv,    // (B,2)  [num_nodes, num_leaves]
    float* __restrict__ H,           // (B,N,128) = d_out, init = x
    float* __restrict__ Cst) {       // (B,N,128) ws, init = x
  const int b = blockIdx.x;
  const int tid = threadIdx.x;
  int nodes = nv[2 * b];
  int leaves = nv[2 * b + 1];
  if (nodes > N_) nodes = N_;
  if (leaves < 0) leaves = 0;
  float* Hb = H + (size_t)b * N_ * U_;
  float* Cb = Cst + (size_t)b * N_ * U_;
  const int* chb = child + (size_t)b * N_ * 2;

  // preload weights for row j = tid as packed f16 pairs (192 VGPRs)
  unsigned wreg[192];
  {
    const float* kr = Wk + tid * U_;
#pragma unroll
    for (int i = 0; i < 64; ++i)
      wreg[i] = __builtin_bit_cast(
          unsigned, __builtin_amdgcn_cvt_pkrtz(kr[2 * i], kr[2 * i + 1]));
    const float* rr = Wr + tid * 2 * U_;
#pragma unroll
    for (int i = 0; i < 128; ++i)
      wreg[64 + i] = __builtin_bit_cast(
          unsigned, __builtin_amdgcn_cvt_pkrtz(rr[2 * i], rr[2 * i + 1]));
  }
  const float bj = bias[tid];

#if HAVE_FDOT2
  __shared__ __align__(16) unsigned act2[192];  // packed f16 pairs of [xt, h_ch]
#else
  __shared__ __align__(16) float2 act2[192];
#endif
  __shared__ float zbuf[640];
  __shared__ float2 cbuf[128];

  for (int t = leaves; t < nodes; ++t) {
    // ---- staging: activation vector A = [x_t (128), h_ch (256)] ----
    if (tid < 192) {
      float2 v;
      if (tid < 64) {
        // x_t == H[b,t,:] (row t not yet overwritten at step t)
        v = *(const float2*)(Hb + t * U_ + 2 * tid);
      } else {
        const int m = 2 * tid - 128;            // 0..254, even
        const int cc = chb[t * 2 + (m >> 7)];   // child slot
        v = *(const float2*)(Hb + cc * U_ + (m & 127));
      }
#if HAVE_FDOT2
      act2[tid] =
          __builtin_bit_cast(unsigned, __builtin_amdgcn_cvt_pkrtz(v.x, v.y));
#else
      act2[tid] = v;
#endif
    } else if (tid < 320) {
      // c_ch pairs: gate u needs c_ch[2u], c_ch[2u+1] (same child region)
      const int u = tid - 192;
      const int m = 2 * u;
      const int cc = chb[t * 2 + (m >> 7)];
      cbuf[u] = *(const float2*)(Cb + cc * U_ + (m & 127));
    }
    __syncthreads();

    // ---- z[j] = bias[j] + w_j . A  (thread j = tid) ----
    float acc = bj;
#if HAVE_FDOT2
    {
      const uint4* a4 = (const uint4*)act2;
#pragma unroll
      for (int q = 0; q < 48; ++q) {
        const uint4 v = a4[q];
        acc = __builtin_amdgcn_fdot2(__builtin_bit_cast(h2_t, wreg[4 * q + 0]),
                                     __builtin_bit_cast(h2_t, v.x), acc, false);
        acc = __builtin_amdgcn_fdot2(__builtin_bit_cast(h2_t, wreg[4 * q + 1]),
                                     __builtin_bit_cast(h2_t, v.y), acc, false);
        acc = __builtin_amdgcn_fdot2(__builtin_bit_cast(h2_t, wreg[4 * q + 2]),
                                     __builtin_bit_cast(h2_t, v.z), acc, false);
        acc = __builtin_amdgcn_fdot2(__builtin_bit_cast(h2_t, wreg[4 * q + 3]),
                                     __builtin_bit_cast(h2_t, v.w), acc, false);
      }
    }
#else
    {
#pragma unroll
      for (int i = 0; i < 192; ++i) {
        const float2 a = act2[i];
        const h2_t wh = __builtin_bit_cast(h2_t, wreg[i]);
        acc = __builtin_fmaf((float)wh.x, a.x, acc);
        acc = __builtin_fmaf((float)wh.y, a.y, acc);
      }
    }
#endif
    zbuf[tid] = acc;
    __syncthreads();

    // ---- gates: thread u in [0,128) ----
    if (tid < U_) {
      const float zi  = zbuf[tid];
      const float zf0 = zbuf[U_ + 2 * tid];
      const float zf1 = zbuf[U_ + 2 * tid + 1];
      const float zo  = zbuf[3 * U_ + tid];
      const float zg  = zbuf[4 * U_ + tid];
      const float2 cc = cbuf[tid];
      const float ig = hsig(zi);
      const float f0 = hsig(zf0);
      const float f1 = hsig(zf1);
      const float og = hsig(zo);
      const float gg = tanh_fast(zg);
      const float cn = cc.x * f0 + cc.y * f1 + ig * gg;
      const float hn = og * tanh_fast(cn);
      Hb[t * U_ + tid] = hn;
      Cb[t * U_ + tid] = cn;
    }
    __syncthreads();
  }

  // zero rows t >= num_nodes (valid mask)
  const int total = (N_ - nodes) * U_;
  for (int idx = tid; idx < total; idx += 640)
    Hb[nodes * U_ + idx] = 0.f;
}

extern "C" void kernel_launch(void* const* d_in, const int* in_sizes, int n_in,
                              void* d_out, int out_size, void* d_ws,
                              size_t ws_size, hipStream_t stream) {
  const float* state = (const float*)d_in[0];  // (B,N,E)
  const float* tk    = (const float*)d_in[1];  // (E,U)
  const float* Wk    = (const float*)d_in[2];  // (5U,U)
  const float* Wr    = (const float*)d_in[3];  // (5U,2U)
  const float* bias  = (const float*)d_in[4];  // (5U,1)
  const int*   child = (const int*)d_in[5];    // (B,N,2)
  const int*   nvp   = (const int*)d_in[6];    // (B,2)
  float* H = (float*)d_out;                    // (B,N,U)
  float* C = (float*)d_ws;                     // (B,N,U) scratch

  x_gemm<<<M_ / 64, 256, 0, stream>>>(state, tk, H, C);
  tree_scan<<<B_, 640, 0, stream>>>(Wk, Wr, bias, child, nvp, H, C);
}

// Round 2
// 1282.715 us; speedup vs baseline: 2.2450x; 2.2450x over previous
//
#include <hip/hip_runtime.h>
#include <hip/hip_bf16.h>

#define B_ 128
#define N_ 1024
#define E_ 300
#define U_ 128
#define M_ (B_ * N_)   // 131072
#define Z_ (5 * U_)    // 640

typedef __attribute__((ext_vector_type(8))) short bf16x8;
typedef __attribute__((ext_vector_type(4))) float f32x4;
typedef _Float16 h2_t __attribute__((ext_vector_type(2)));

__device__ __forceinline__ short f2bf(float f) {
  unsigned u = __builtin_bit_cast(unsigned, f);
  u = (u + 0x7fffu + ((u >> 16) & 1u)) >> 16;
  return (short)u;
}

__device__ __forceinline__ float hsig(float z) {
  float v = __builtin_fmaf(z, 0.2f, 0.5f);
  v = v < 0.f ? 0.f : v;
  v = v > 1.f ? 1.f : v;
  return v;
}

__device__ __forceinline__ float tanh_fast(float x) {
  float p = __expf(2.f * x);
  return 1.f - 2.f * __builtin_amdgcn_rcpf(p + 1.f);
}

// ---------------- Kernel 1: x = relu(state @ Tk) -> H (d_out) and C (ws) ---
__global__ __launch_bounds__(256) void x_gemm(
    const float* __restrict__ A, const float* __restrict__ W,
    float* __restrict__ H, float* __restrict__ C) {
  __shared__ __align__(16) short As[64][40];
  __shared__ __align__(16) short Ws[128][40];
  const int tid = threadIdx.x;
  const int m0 = blockIdx.x * 64;
  f32x4 acc[8] = {};
  const int lane = tid & 63, wv = tid >> 6;
  const int lr = lane & 15, lg = lane >> 4;

  for (int kc = 0; kc < 10; ++kc) {
    const int k0 = kc * 32;
    {
      const int row = tid >> 2, kk = (tid & 3) * 8;
      const float* src = A + (size_t)(m0 + row) * E_ + k0 + kk;
      bf16x8 v;
      if (k0 + 32 <= E_) {
#pragma unroll
        for (int i = 0; i < 8; ++i) v[i] = f2bf(src[i]);
      } else {
#pragma unroll
        for (int i = 0; i < 8; ++i)
          v[i] = (k0 + kk + i < E_) ? f2bf(src[i]) : (short)0;
      }
      *(bf16x8*)&As[row][kk] = v;
    }
#pragma unroll
    for (int s = 0; s < 2; ++s) {
      const int slot = tid + s * 256;
      const int n = slot & 127, kg = slot >> 7;
      bf16x8 v;
      if (k0 + 32 <= E_) {
#pragma unroll
        for (int i = 0; i < 8; ++i) v[i] = f2bf(W[(k0 + kg * 8 + i) * U_ + n]);
      } else {
#pragma unroll
        for (int i = 0; i < 8; ++i) {
          const int k = k0 + kg * 8 + i;
          v[i] = (k < E_) ? f2bf(W[k * U_ + n]) : (short)0;
        }
      }
      *(bf16x8*)&Ws[n][kg * 8] = v;
    }
    __syncthreads();
    bf16x8 a = *(const bf16x8*)&As[wv * 16 + lr][lg * 8];
#pragma unroll
    for (int nt = 0; nt < 8; ++nt) {
      bf16x8 b = *(const bf16x8*)&Ws[nt * 16 + lr][lg * 8];
      acc[nt] = __builtin_amdgcn_mfma_f32_16x16x32_bf16(a, b, acc[nt], 0, 0, 0);
    }
    __syncthreads();
  }
#pragma unroll
  for (int nt = 0; nt < 8; ++nt) {
#pragma unroll
    for (int r = 0; r < 4; ++r) {
      const int m = m0 + wv * 16 + lg * 4 + r;
      const int n = nt * 16 + lr;
      float v = acc[nt][r];
      v = v > 0.f ? v : 0.f;
      H[(size_t)m * U_ + n] = v;
      C[(size_t)m * U_ + n] = v;
    }
  }
}

// ---------------- Kernel 2: xz = x @ K^T + bias (f16 out) ------------------
// x: (M_,128) f32 (read from H), K: (640,128) f32 row-major = [n][k].
// BM=64, BN=128, BK=32; grid (M_/64, 5).
__global__ __launch_bounds__(256) void xz_gemm(
    const float* __restrict__ X, const float* __restrict__ K,
    const float* __restrict__ bias, _Float16* __restrict__ XZ) {
  __shared__ __align__(16) short As[64][40];
  __shared__ __align__(16) short Ws[128][40];
  const int tid = threadIdx.x;
  const int m0 = blockIdx.x * 64;
  const int n0 = blockIdx.y * 128;
  f32x4 acc[8] = {};
  const int lane = tid & 63, wv = tid >> 6;
  const int lr = lane & 15, lg = lane >> 4;

  for (int kc = 0; kc < 4; ++kc) {
    const int k0 = kc * 32;
    {
      const int row = tid >> 2, kk = (tid & 3) * 8;
      const float* src = X + (size_t)(m0 + row) * U_ + k0 + kk;
      bf16x8 v;
#pragma unroll
      for (int i = 0; i < 8; ++i) v[i] = f2bf(src[i]);
      *(bf16x8*)&As[row][kk] = v;
    }
#pragma unroll
    for (int s = 0; s < 2; ++s) {
      const int slot = tid + s * 256;
      const int n = slot >> 2, kk = (slot & 3) * 8;
      const float* src = K + (size_t)(n0 + n) * U_ + k0 + kk;
      bf16x8 v;
#pragma unroll
      for (int i = 0; i < 8; ++i) v[i] = f2bf(src[i]);
      *(bf16x8*)&Ws[n][kk] = v;
    }
    __syncthreads();
    bf16x8 a = *(const bf16x8*)&As[wv * 16 + lr][lg * 8];
#pragma unroll
    for (int nt = 0; nt < 8; ++nt) {
      bf16x8 b = *(const bf16x8*)&Ws[nt * 16 + lr][lg * 8];
      acc[nt] = __builtin_amdgcn_mfma_f32_16x16x32_bf16(a, b, acc[nt], 0, 0, 0);
    }
    __syncthreads();
  }
#pragma unroll
  for (int nt = 0; nt < 8; ++nt) {
    const int n = n0 + nt * 16 + lr;
    const float bv = bias[n];
#pragma unroll
    for (int r = 0; r < 4; ++r) {
      const int m = m0 + wv * 16 + lg * 4 + r;
      XZ[(size_t)m * Z_ + n] = (_Float16)(acc[nt][r] + bv);
    }
  }
}

// ---------------- Kernel 3: per-batch scan, R-weights in registers ---------
// 640 threads; thread j owns z-row j: 256 R-weights = 128 packed f16 pairs.
__global__ __launch_bounds__(640, 3) void tree_scan2(
    const float* __restrict__ Wr,      // (640,256)
    const int*   __restrict__ child,   // (B,N,2)
    const int*   __restrict__ nv,      // (B,2)
    const _Float16* __restrict__ XZ,   // (B,N,640)
    float* __restrict__ H,             // (B,N,128)
    float* __restrict__ Cst) {         // (B,N,128)
  const int b = blockIdx.x;
  const int tid = threadIdx.x;
  int nodes = nv[2 * b];
  int leaves = nv[2 * b + 1];
  if (nodes > N_) nodes = N_;
  if (leaves < 0) leaves = 0;
  float* Hb = H + (size_t)b * N_ * U_;
  float* Cb = Cst + (size_t)b * N_ * U_;
  const int* chb = child + (size_t)b * N_ * 2;
  const _Float16* xzb = XZ + (size_t)b * N_ * Z_;

  // preload R row j=tid as 128 packed f16 pairs
  unsigned wreg[128];
  {
    const float* rr = Wr + (size_t)tid * 2 * U_;
#pragma unroll
    for (int i = 0; i < 128; ++i)
      wreg[i] = __builtin_bit_cast(
          unsigned, __builtin_amdgcn_cvt_pkrtz(rr[2 * i], rr[2 * i + 1]));
  }

  __shared__ __align__(16) unsigned act2[128];  // packed f16 pairs of h_ch
  __shared__ float zbuf[Z_];
  __shared__ float2 cbuf[128];

  if (leaves < nodes) {
    // prefetched state for step t
    float zc = (float)xzb[(size_t)leaves * Z_ + tid];
    int cc = 0;
    if (tid < 256) cc = chb[2 * leaves + ((tid & 127) >> 6)];

    for (int t = leaves; t < nodes; ++t) {
      // ---- prefetch for t+1 (static data, independent) ----
      const int tn = (t + 1 < N_) ? t + 1 : t;
      const float zn = (float)xzb[(size_t)tn * Z_ + tid];
      int ccn = 0;
      if (tid < 256) ccn = chb[2 * tn + ((tid & 127) >> 6)];

      // ---- staging: h_ch (128 pairs), c_ch (128 pairs) ----
      if (tid < 128) {
        const float2 v = *(const float2*)(Hb + (size_t)cc * U_ + ((2 * tid) & 127));
        act2[tid] =
            __builtin_bit_cast(unsigned, __builtin_amdgcn_cvt_pkrtz(v.x, v.y));
      } else if (tid < 256) {
        const int u = tid - 128;
        cbuf[u] = *(const float2*)(Cb + (size_t)cc * U_ + ((2 * u) & 127));
      }
      __syncthreads();

      // ---- z[j] = xz[t][j] + R_j . h_ch ----
      float s0 = zc, s1 = 0.f, s2 = 0.f, s3 = 0.f;
      {
        const uint4* a4 = (const uint4*)act2;
#pragma unroll
        for (int q = 0; q < 32; ++q) {
          const uint4 v = a4[q];
          s0 = __builtin_amdgcn_fdot2(__builtin_bit_cast(h2_t, wreg[4 * q + 0]),
                                      __builtin_bit_cast(h2_t, v.x), s0, false);
          s1 = __builtin_amdgcn_fdot2(__builtin_bit_cast(h2_t, wreg[4 * q + 1]),
                                      __builtin_bit_cast(h2_t, v.y), s1, false);
          s2 = __builtin_amdgcn_fdot2(__builtin_bit_cast(h2_t, wreg[4 * q + 2]),
                                      __builtin_bit_cast(h2_t, v.z), s2, false);
          s3 = __builtin_amdgcn_fdot2(__builtin_bit_cast(h2_t, wreg[4 * q + 3]),
                                      __builtin_bit_cast(h2_t, v.w), s3, false);
        }
      }
      zbuf[tid] = (s0 + s1) + (s2 + s3);
      __syncthreads();

      // ---- gates ----
      if (tid < U_) {
        const float zi = zbuf[tid];
        const float2 zf = *(const float2*)&zbuf[U_ + 2 * tid];
        const float zo = zbuf[3 * U_ + tid];
        const float zg = zbuf[4 * U_ + tid];
        const float2 ccv = cbuf[tid];
        const float ig = hsig(zi);
        const float f0 = hsig(zf.x);
        const float f1 = hsig(zf.y);
        const float og = hsig(zo);
        const float gg = tanh_fast(zg);
        const float cn = ccv.x * f0 + ccv.y * f1 + ig * gg;
        const float hn = og * tanh_fast(cn);
        Hb[(size_t)t * U_ + tid] = hn;
        Cb[(size_t)t * U_ + tid] = cn;
      }
      __syncthreads();

      zc = zn;
      cc = ccn;
    }
  }

  // zero rows t >= num_nodes
  const int total = (N_ - nodes) * U_;
  for (int idx = tid; idx < total; idx += 640)
    Hb[(size_t)nodes * U_ + idx] = 0.f;
}

// ---------------- Fallback scan (R1 version, known-correct) ----------------
__global__ __launch_bounds__(640, 1) void tree_scan_fb(
    const float* __restrict__ Wk, const float* __restrict__ Wr,
    const float* __restrict__ bias, const int* __restrict__ child,
    const int* __restrict__ nv, float* __restrict__ H,
    float* __restrict__ Cst) {
  const int b = blockIdx.x;
  const int tid = threadIdx.x;
  int nodes = nv[2 * b];
  int leaves = nv[2 * b + 1];
  if (nodes > N_) nodes = N_;
  if (leaves < 0) leaves = 0;
  float* Hb = H + (size_t)b * N_ * U_;
  float* Cb = Cst + (size_t)b * N_ * U_;
  const int* chb = child + (size_t)b * N_ * 2;

  unsigned wreg[192];
  {
    const float* kr = Wk + tid * U_;
#pragma unroll
    for (int i = 0; i < 64; ++i)
      wreg[i] = __builtin_bit_cast(
          unsigned, __builtin_amdgcn_cvt_pkrtz(kr[2 * i], kr[2 * i + 1]));
    const float* rr = Wr + tid * 2 * U_;
#pragma unroll
    for (int i = 0; i < 128; ++i)
      wreg[64 + i] = __builtin_bit_cast(
          unsigned, __builtin_amdgcn_cvt_pkrtz(rr[2 * i], rr[2 * i + 1]));
  }
  const float bj = bias[tid];

  __shared__ __align__(16) unsigned act2[192];
  __shared__ float zbuf[640];
  __shared__ float2 cbuf[128];

  for (int t = leaves; t < nodes; ++t) {
    if (tid < 192) {
      float2 v;
      if (tid < 64) {
        v = *(const float2*)(Hb + t * U_ + 2 * tid);
      } else {
        const int m = 2 * tid - 128;
        const int cc = chb[t * 2 + (m >> 7)];
        v = *(const float2*)(Hb + cc * U_ + (m & 127));
      }
      act2[tid] =
          __builtin_bit_cast(unsigned, __builtin_amdgcn_cvt_pkrtz(v.x, v.y));
    } else if (tid < 320) {
      const int u = tid - 192;
      const int m = 2 * u;
      const int cc = chb[t * 2 + (m >> 7)];
      cbuf[u] = *(const float2*)(Cb + cc * U_ + (m & 127));
    }
    __syncthreads();

    float acc = bj;
    {
      const uint4* a4 = (const uint4*)act2;
#pragma unroll
      for (int q = 0; q < 48; ++q) {
        const uint4 v = a4[q];
        acc = __builtin_amdgcn_fdot2(__builtin_bit_cast(h2_t, wreg[4 * q + 0]),
                                     __builtin_bit_cast(h2_t, v.x), acc, false);
        acc = __builtin_amdgcn_fdot2(__builtin_bit_cast(h2_t, wreg[4 * q + 1]),
                                     __builtin_bit_cast(h2_t, v.y), acc, false);
        acc = __builtin_amdgcn_fdot2(__builtin_bit_cast(h2_t, wreg[4 * q + 2]),
                                     __builtin_bit_cast(h2_t, v.z), acc, false);
        acc = __builtin_amdgcn_fdot2(__builtin_bit_cast(h2_t, wreg[4 * q + 3]),
                                     __builtin_bit_cast(h2_t, v.w), acc, false);
      }
    }
    zbuf[tid] = acc;
    __syncthreads();

    if (tid < U_) {
      const float zi = zbuf[tid];
      const float zf0 = zbuf[U_ + 2 * tid];
      const float zf1 = zbuf[U_ + 2 * tid + 1];
      const float zo = zbuf[3 * U_ + tid];
      const float zg = zbuf[4 * U_ + tid];
      const float2 cc = cbuf[tid];
      const float ig = hsig(zi);
      const float f0 = hsig(zf0);
      const float f1 = hsig(zf1);
      const float og = hsig(zo);
      const float gg = tanh_fast(zg);
      const float cn = cc.x * f0 + cc.y * f1 + ig * gg;
      const float hn = og * tanh_fast(cn);
      Hb[t * U_ + tid] = hn;
      Cb[t * U_ + tid] = cn;
    }
    __syncthreads();
  }

  const int total = (N_ - nodes) * U_;
  for (int idx = tid; idx < total; idx += 640)
    Hb[nodes * U_ + idx] = 0.f;
}

extern "C" void kernel_launch(void* const* d_in, const int* in_sizes, int n_in,
                              void* d_out, int out_size, void* d_ws,
                              size_t ws_size, hipStream_t stream) {
  const float* state = (const float*)d_in[0];
  const float* tk    = (const float*)d_in[1];
  const float* Wk    = (const float*)d_in[2];
  const float* Wr    = (const float*)d_in[3];
  const float* bias  = (const float*)d_in[4];
  const int*   child = (const int*)d_in[5];
  const int*   nvp   = (const int*)d_in[6];
  float* H = (float*)d_out;

  const size_t c_bytes = (size_t)M_ * U_ * sizeof(float);      // 64 MiB
  const size_t xz_bytes = (size_t)M_ * Z_ * sizeof(_Float16);  // 160 MiB
  float* C = (float*)d_ws;

  x_gemm<<<M_ / 64, 256, 0, stream>>>(state, tk, H, C);

  if (ws_size >= c_bytes + xz_bytes) {
    _Float16* XZ = (_Float16*)((char*)d_ws + c_bytes);
    xz_gemm<<<dim3(M_ / 64, 5), 256, 0, stream>>>(H, Wk, bias, XZ);
    tree_scan2<<<B_, 640, 0, stream>>>(Wr, child, nvp, XZ, H, C);
  } else {
    tree_scan_fb<<<B_, 640, 0, stream>>>(Wk, Wr, bias, child, nvp, H, C);
  }
}

// Round 3
// 1024.723 us; speedup vs baseline: 2.8102x; 1.2518x over previous
//
#include <hip/hip_runtime.h>
#include <hip/hip_bf16.h>

#define B_ 128
#define N_ 1024
#define E_ 300
#define U_ 128
#define M_ (B_ * N_)   // 131072
#define Z_ (5 * U_)    // 640

typedef __attribute__((ext_vector_type(8))) short bf16x8;
typedef __attribute__((ext_vector_type(4))) float f32x4;
typedef _Float16 h2_t __attribute__((ext_vector_type(2)));
typedef _Float16 f16x4 __attribute__((ext_vector_type(4)));
typedef _Float16 f16x8 __attribute__((ext_vector_type(8)));

__device__ __forceinline__ short f2bf(float f) {
  unsigned u = __builtin_bit_cast(unsigned, f);
  u = (u + 0x7fffu + ((u >> 16) & 1u)) >> 16;
  return (short)u;
}

__device__ __forceinline__ float hsig(float z) {
  float v = __builtin_fmaf(z, 0.2f, 0.5f);
  v = v < 0.f ? 0.f : v;
  v = v > 1.f ? 1.f : v;
  return v;
}

__device__ __forceinline__ float tanh_fast(float x) {
  float p = __expf(2.f * x);
  return 1.f - 2.f * __builtin_amdgcn_rcpf(p + 1.f);
}

// ---------------- Kernel 1: x = relu(state @ Tk) -> H (d_out) and C (ws) ---
__global__ __launch_bounds__(256) void x_gemm(
    const float* __restrict__ A, const float* __restrict__ W,
    float* __restrict__ H, float* __restrict__ C) {
  __shared__ __align__(16) short As[64][40];
  __shared__ __align__(16) short Ws[128][40];
  const int tid = threadIdx.x;
  const int m0 = blockIdx.x * 64;
  f32x4 acc[8] = {};
  const int lane = tid & 63, wv = tid >> 6;
  const int lr = lane & 15, lg = lane >> 4;

  for (int kc = 0; kc < 10; ++kc) {
    const int k0 = kc * 32;
    {
      const int row = tid >> 2, kk = (tid & 3) * 8;
      const float* src = A + (size_t)(m0 + row) * E_ + k0 + kk;
      bf16x8 v;
      if (k0 + 32 <= E_) {
#pragma unroll
        for (int i = 0; i < 8; ++i) v[i] = f2bf(src[i]);
      } else {
#pragma unroll
        for (int i = 0; i < 8; ++i)
          v[i] = (k0 + kk + i < E_) ? f2bf(src[i]) : (short)0;
      }
      *(bf16x8*)&As[row][kk] = v;
    }
#pragma unroll
    for (int s = 0; s < 2; ++s) {
      const int slot = tid + s * 256;
      const int n = slot & 127, kg = slot >> 7;
      bf16x8 v;
      if (k0 + 32 <= E_) {
#pragma unroll
        for (int i = 0; i < 8; ++i) v[i] = f2bf(W[(k0 + kg * 8 + i) * U_ + n]);
      } else {
#pragma unroll
        for (int i = 0; i < 8; ++i) {
          const int k = k0 + kg * 8 + i;
          v[i] = (k < E_) ? f2bf(W[k * U_ + n]) : (short)0;
        }
      }
      *(bf16x8*)&Ws[n][kg * 8] = v;
    }
    __syncthreads();
    bf16x8 a = *(const bf16x8*)&As[wv * 16 + lr][lg * 8];
#pragma unroll
    for (int nt = 0; nt < 8; ++nt) {
      bf16x8 b = *(const bf16x8*)&Ws[nt * 16 + lr][lg * 8];
      acc[nt] = __builtin_amdgcn_mfma_f32_16x16x32_bf16(a, b, acc[nt], 0, 0, 0);
    }
    __syncthreads();
  }
#pragma unroll
  for (int nt = 0; nt < 8; ++nt) {
#pragma unroll
    for (int r = 0; r < 4; ++r) {
      const int m = m0 + wv * 16 + lg * 4 + r;
      const int n = nt * 16 + lr;
      float v = acc[nt][r];
      v = v > 0.f ? v : 0.f;
      H[(size_t)m * U_ + n] = v;
      C[(size_t)m * U_ + n] = v;
    }
  }
}

// ---------------- Kernel 2: xz = x @ K^T + bias (f16 out) ------------------
__global__ __launch_bounds__(256) void xz_gemm(
    const float* __restrict__ X, const float* __restrict__ K,
    const float* __restrict__ bias, _Float16* __restrict__ XZ) {
  __shared__ __align__(16) short As[64][40];
  __shared__ __align__(16) short Ws[128][40];
  const int tid = threadIdx.x;
  const int m0 = blockIdx.x * 64;
  const int n0 = blockIdx.y * 128;
  f32x4 acc[8] = {};
  const int lane = tid & 63, wv = tid >> 6;
  const int lr = lane & 15, lg = lane >> 4;

  for (int kc = 0; kc < 4; ++kc) {
    const int k0 = kc * 32;
    {
      const int row = tid >> 2, kk = (tid & 3) * 8;
      const float* src = X + (size_t)(m0 + row) * U_ + k0 + kk;
      bf16x8 v;
#pragma unroll
      for (int i = 0; i < 8; ++i) v[i] = f2bf(src[i]);
      *(bf16x8*)&As[row][kk] = v;
    }
#pragma unroll
    for (int s = 0; s < 2; ++s) {
      const int slot = tid + s * 256;
      const int n = slot >> 2, kk = (slot & 3) * 8;
      const float* src = K + (size_t)(n0 + n) * U_ + k0 + kk;
      bf16x8 v;
#pragma unroll
      for (int i = 0; i < 8; ++i) v[i] = f2bf(src[i]);
      *(bf16x8*)&Ws[n][kk] = v;
    }
    __syncthreads();
    bf16x8 a = *(const bf16x8*)&As[wv * 16 + lr][lg * 8];
#pragma unroll
    for (int nt = 0; nt < 8; ++nt) {
      bf16x8 b = *(const bf16x8*)&Ws[nt * 16 + lr][lg * 8];
      acc[nt] = __builtin_amdgcn_mfma_f32_16x16x32_bf16(a, b, acc[nt], 0, 0, 0);
    }
    __syncthreads();
  }
#pragma unroll
  for (int nt = 0; nt < 8; ++nt) {
    const int n = n0 + nt * 16 + lr;
    const float bv = bias[n];
#pragma unroll
    for (int r = 0; r < 4; ++r) {
      const int m = m0 + wv * 16 + lg * 4 + r;
      XZ[(size_t)m * Z_ + n] = (_Float16)(acc[nt][r] + bv);
    }
  }
}

// ---------------- Kernel 3: per-batch scan, MFMA GEMV, R in A-fragments ----
// 512 threads = 8 waves. Wave w owns z-rows [80w, 80w+80) as 5 row-tiles.
// A-fragment (16x32 f16): lane holds A[row=80w+16rt+(lane&15)][k=32kt+(lane>>4)*8+i].
// B broadcast: B[k][col] = h[k] for all cols -> every output column equals z.
__global__ __launch_bounds__(512, 2) void tree_scan3(
    const float* __restrict__ Wr,      // (640,256)
    const int*   __restrict__ child,   // (B,N,2)
    const int*   __restrict__ nv,      // (B,2)
    const _Float16* __restrict__ XZ,   // (B,N,640)
    float* __restrict__ H,             // (B,N,128)
    float* __restrict__ Cst) {         // (B,N,128)
  const int b = blockIdx.x;
  const int tid = threadIdx.x;
  const int lane = tid & 63, w = tid >> 6;
  const int col = lane & 15, hi = lane >> 4;
  int nodes = nv[2 * b];
  int leaves = nv[2 * b + 1];
  if (nodes > N_) nodes = N_;
  if (leaves < 0) leaves = 0;
  float* Hb = H + (size_t)b * N_ * U_;
  float* Cb = Cst + (size_t)b * N_ * U_;
  const int* chb = child + (size_t)b * N_ * 2;
  const _Float16* xzb = XZ + (size_t)b * N_ * Z_;

  // ---- preload R as MFMA A-fragments: 5 rt x 8 kt x 8 f16 = 160 VGPRs ----
  f16x8 afrag[5][8];
  {
    const int r0 = 80 * w + col;
    const int kb = hi * 8;
#pragma unroll
    for (int rt = 0; rt < 5; ++rt) {
      const float* rsrc = Wr + (size_t)(r0 + 16 * rt) * 256 + kb;
#pragma unroll
      for (int kt = 0; kt < 8; ++kt) {
        const float* s = rsrc + 32 * kt;
#pragma unroll
        for (int i = 0; i < 8; ++i) afrag[rt][kt][i] = (_Float16)s[i];
      }
    }
  }

  __shared__ __align__(16) unsigned act2[128];  // h_ch as 128 packed f16 pairs
  __shared__ float zbuf[Z_];
  __shared__ float2 cbuf[128];

  const bool is_writer = (col < 5);
  const int rbase = 80 * w + 16 * col + 4 * hi;  // z-rows for writer lanes

  if (leaves < nodes) {
    // initial prefetch for t = leaves
    int cc = 0;
    if (tid >= 256) cc = chb[2 * leaves + ((tid & 127) >> 6)];
    f16x4 xzv = {};
    if (is_writer) xzv = *(const f16x4*)(xzb + (size_t)leaves * Z_ + rbase);

    for (int t = leaves; t < nodes; ++t) {
      // ---- prefetch t+1 (static data) ----
      const int tn = (t + 1 < N_) ? t + 1 : t;
      int ccn = 0;
      if (tid >= 256) ccn = chb[2 * tn + ((tid & 127) >> 6)];
      f16x4 xzn = {};
      if (is_writer) xzn = *(const f16x4*)(xzb + (size_t)tn * Z_ + rbase);

      // ---- staging: waves 4-7 gather h_ch, c_ch ----
      if (tid >= 384) {           // c pairs: u in [0,128)
        const int u = tid - 384;
        cbuf[u] = *(const float2*)(Cb + (size_t)cc * U_ + ((2 * u) & 127));
      } else if (tid >= 256) {    // h pairs: p in [0,128)
        const int p = tid - 256;
        const float2 v = *(const float2*)(Hb + (size_t)cc * U_ + ((2 * p) & 127));
        act2[p] =
            __builtin_bit_cast(unsigned, __builtin_amdgcn_cvt_pkrtz(v.x, v.y));
      }
      __syncthreads();

      // ---- MFMA GEMV: z = R . h_ch (+ xz) ----
      f16x8 bfrag[8];
      {
        const _Float16* hp = (const _Float16*)act2 + hi * 8;
#pragma unroll
        for (int kt = 0; kt < 8; ++kt)
          bfrag[kt] = *(const f16x8*)(hp + 32 * kt);
      }
      f32x4 acc[5] = {};
#pragma unroll
      for (int kt = 0; kt < 8; ++kt) {
#pragma unroll
        for (int rt = 0; rt < 5; ++rt)
          acc[rt] = __builtin_amdgcn_mfma_f32_16x16x32_f16(
              afrag[rt][kt], bfrag[kt], acc[rt], 0, 0, 0);
      }
      if (is_writer) {
        f32x4 zv = {};
#pragma unroll
        for (int c = 0; c < 5; ++c)
          if (col == c) zv = acc[c];
        zbuf[rbase + 0] = zv[0] + (float)xzv[0];
        zbuf[rbase + 1] = zv[1] + (float)xzv[1];
        zbuf[rbase + 2] = zv[2] + (float)xzv[2];
        zbuf[rbase + 3] = zv[3] + (float)xzv[3];
      }
      __syncthreads();

      // ---- gates: waves 2-3 ----
      if (tid >= 128 && tid < 256) {
        const int u = tid - 128;
        const float zi = zbuf[u];
        const float2 zf = *(const float2*)&zbuf[U_ + 2 * u];
        const float zo = zbuf[3 * U_ + u];
        const float zg = zbuf[4 * U_ + u];
        const float2 ccv = cbuf[u];
        const float ig = hsig(zi);
        const float f0 = hsig(zf.x);
        const float f1 = hsig(zf.y);
        const float og = hsig(zo);
        const float gg = tanh_fast(zg);
        const float cn = ccv.x * f0 + ccv.y * f1 + ig * gg;
        const float hn = og * tanh_fast(cn);
        Hb[(size_t)t * U_ + u] = hn;
        Cb[(size_t)t * U_ + u] = cn;
      }
      __syncthreads();

      cc = ccn;
      xzv = xzn;
    }
  }

  // zero rows t >= num_nodes
  const int total = (N_ - nodes) * U_;
  for (int idx = tid; idx < total; idx += 512)
    Hb[(size_t)nodes * U_ + idx] = 0.f;
}

// ---------------- Fallback scan (R1 version, known-correct) ----------------
__global__ __launch_bounds__(640, 1) void tree_scan_fb(
    const float* __restrict__ Wk, const float* __restrict__ Wr,
    const float* __restrict__ bias, const int* __restrict__ child,
    const int* __restrict__ nv, float* __restrict__ H,
    float* __restrict__ Cst) {
  const int b = blockIdx.x;
  const int tid = threadIdx.x;
  int nodes = nv[2 * b];
  int leaves = nv[2 * b + 1];
  if (nodes > N_) nodes = N_;
  if (leaves < 0) leaves = 0;
  float* Hb = H + (size_t)b * N_ * U_;
  float* Cb = Cst + (size_t)b * N_ * U_;
  const int* chb = child + (size_t)b * N_ * 2;

  unsigned wreg[192];
  {
    const float* kr = Wk + tid * U_;
#pragma unroll
    for (int i = 0; i < 64; ++i)
      wreg[i] = __builtin_bit_cast(
          unsigned, __builtin_amdgcn_cvt_pkrtz(kr[2 * i], kr[2 * i + 1]));
    const float* rr = Wr + tid * 2 * U_;
#pragma unroll
    for (int i = 0; i < 128; ++i)
      wreg[64 + i] = __builtin_bit_cast(
          unsigned, __builtin_amdgcn_cvt_pkrtz(rr[2 * i], rr[2 * i + 1]));
  }
  const float bj = bias[tid];

  __shared__ __align__(16) unsigned act2[192];
  __shared__ float zbuf[640];
  __shared__ float2 cbuf[128];

  for (int t = leaves; t < nodes; ++t) {
    if (tid < 192) {
      float2 v;
      if (tid < 64) {
        v = *(const float2*)(Hb + t * U_ + 2 * tid);
      } else {
        const int m = 2 * tid - 128;
        const int cc = chb[t * 2 + (m >> 7)];
        v = *(const float2*)(Hb + cc * U_ + (m & 127));
      }
      act2[tid] =
          __builtin_bit_cast(unsigned, __builtin_amdgcn_cvt_pkrtz(v.x, v.y));
    } else if (tid < 320) {
      const int u = tid - 192;
      const int m = 2 * u;
      const int cc = chb[t * 2 + (m >> 7)];
      cbuf[u] = *(const float2*)(Cb + cc * U_ + (m & 127));
    }
    __syncthreads();

    float acc = bj;
    {
      const uint4* a4 = (const uint4*)act2;
#pragma unroll
      for (int q = 0; q < 48; ++q) {
        const uint4 v = a4[q];
        acc = __builtin_amdgcn_fdot2(__builtin_bit_cast(h2_t, wreg[4 * q + 0]),
                                     __builtin_bit_cast(h2_t, v.x), acc, false);
        acc = __builtin_amdgcn_fdot2(__builtin_bit_cast(h2_t, wreg[4 * q + 1]),
                                     __builtin_bit_cast(h2_t, v.y), acc, false);
        acc = __builtin_amdgcn_fdot2(__builtin_bit_cast(h2_t, wreg[4 * q + 2]),
                                     __builtin_bit_cast(h2_t, v.z), acc, false);
        acc = __builtin_amdgcn_fdot2(__builtin_bit_cast(h2_t, wreg[4 * q + 3]),
                                     __builtin_bit_cast(h2_t, v.w), acc, false);
      }
    }
    zbuf[tid] = acc;
    __syncthreads();

    if (tid < U_) {
      const float zi = zbuf[tid];
      const float zf0 = zbuf[U_ + 2 * tid];
      const float zf1 = zbuf[U_ + 2 * tid + 1];
      const float zo = zbuf[3 * U_ + tid];
      const float zg = zbuf[4 * U_ + tid];
      const float2 cc = cbuf[tid];
      const float ig = hsig(zi);
      const float f0 = hsig(zf0);
      const float f1 = hsig(zf1);
      const float og = hsig(zo);
      const float gg = tanh_fast(zg);
      const float cn = cc.x * f0 + cc.y * f1 + ig * gg;
      const float hn = og * tanh_fast(cn);
      Hb[t * U_ + tid] = hn;
      Cb[t * U_ + tid] = cn;
    }
    __syncthreads();
  }

  const int total = (N_ - nodes) * U_;
  for (int idx = tid; idx < total; idx += 640)
    Hb[nodes * U_ + idx] = 0.f;
}

extern "C" void kernel_launch(void* const* d_in, const int* in_sizes, int n_in,
                              void* d_out, int out_size, void* d_ws,
                              size_t ws_size, hipStream_t stream) {
  const float* state = (const float*)d_in[0];
  const float* tk    = (const float*)d_in[1];
  const float* Wk    = (const float*)d_in[2];
  const float* Wr    = (const float*)d_in[3];
  const float* bias  = (const float*)d_in[4];
  const int*   child = (const int*)d_in[5];
  const int*   nvp   = (const int*)d_in[6];
  float* H = (float*)d_out;

  const size_t c_bytes = (size_t)M_ * U_ * sizeof(float);      // 64 MiB
  const size_t xz_bytes = (size_t)M_ * Z_ * sizeof(_Float16);  // 160 MiB
  float* C = (float*)d_ws;

  x_gemm<<<M_ / 64, 256, 0, stream>>>(state, tk, H, C);

  if (ws_size >= c_bytes + xz_bytes) {
    _Float16* XZ = (_Float16*)((char*)d_ws + c_bytes);
    xz_gemm<<<dim3(M_ / 64, 5), 256, 0, stream>>>(H, Wk, bias, XZ);
    tree_scan3<<<B_, 512, 0, stream>>>(Wr, child, nvp, XZ, H, C);
  } else {
    tree_scan_fb<<<B_, 640, 0, stream>>>(Wk, Wr, bias, child, nvp, H, C);
  }
}